// Round 1
// baseline (560.789 us; speedup 1.0000x reference)
//
#include <hip/hip_runtime.h>
#include <hip/hip_bf16.h>

#define T_TOK 8192
#define DDIM 2048
#define ODIM 2048
#define NEXP 8
#define BK 64

typedef __attribute__((ext_vector_type(8))) short short8;
typedef __attribute__((ext_vector_type(4))) float f32x4;

__device__ inline unsigned short f2bf(float f) {
    union { float f; unsigned u; } c; c.f = f;
    unsigned u = c.u;
    u += 0x7FFF + ((u >> 16) & 1);   // round-to-nearest-even
    return (unsigned short)(u >> 16);
}

// ---------------- router: logits = x @ Wr^T + br ; argmax ; counts ----------------
__global__ __launch_bounds__(256) void router_kernel(
        const float* __restrict__ x, const float* __restrict__ Wr,
        const float* __restrict__ br, int* __restrict__ layer,
        int* __restrict__ counts) {
    int lane = threadIdx.x & 63;
    int wave = threadIdx.x >> 6;
    int t = blockIdx.x * 4 + wave;
    const float4* xr = (const float4*)(x + (size_t)t * DDIM);
    float acc[NEXP];
#pragma unroll
    for (int e = 0; e < NEXP; ++e) acc[e] = 0.f;
#pragma unroll
    for (int it = 0; it < 8; ++it) {
        int d4 = it * 64 + lane;           // float4 index within row
        float4 xv = xr[d4];
#pragma unroll
        for (int e = 0; e < NEXP; ++e) {
            float4 wv = ((const float4*)(Wr + e * DDIM))[d4];
            acc[e] += xv.x * wv.x + xv.y * wv.y + xv.z * wv.z + xv.w * wv.w;
        }
    }
#pragma unroll
    for (int e = 0; e < NEXP; ++e) {
        float v = acc[e];
#pragma unroll
        for (int off = 32; off > 0; off >>= 1) v += __shfl_xor(v, off);
        acc[e] = v;
    }
    if (lane == 0) {
        float best = -1e30f; int arg = 0;
#pragma unroll
        for (int e = 0; e < NEXP; ++e) {
            float v = acc[e] + br[e];
            if (v > best) { best = v; arg = e; }   // strict > keeps first max (np tie-break)
        }
        layer[t] = arg;
        atomicAdd(&counts[arg], 1);
    }
}

// ---------------- prefix offsets + load-balance loss ----------------
__global__ void prefix_loss_kernel(const int* __restrict__ counts,
                                   int* __restrict__ start, int* __restrict__ cursor,
                                   float* __restrict__ loss_out) {
    if (threadIdx.x == 0) {
        int s = 0;
        for (int e = 0; e < NEXP; ++e) { start[e] = s; cursor[e] = s; s += counts[e]; }
        float mean = (float)T_TOK / (float)NEXP;
        float var = 0.f;
        for (int e = 0; e < NEXP; ++e) { float d = (float)counts[e] - mean; var += d * d; }
        loss_out[0] = (var / (float)NEXP) * 3e-06f;
    }
}

// ---------------- scatter tokens into per-expert buckets ----------------
__global__ __launch_bounds__(256) void scatter_kernel(const int* __restrict__ layer,
                                                      int* __restrict__ cursor,
                                                      int* __restrict__ perm) {
    int t = blockIdx.x * 256 + threadIdx.x;
    int e = layer[t];
    int pos = atomicAdd(&cursor[e], 1);
    perm[pos] = t;
}

// ---------------- grouped GEMM: out[t] = x[t] @ Wp[e]^T + bp[e] ----------------
// 128x128 tile, BK=64, 4 waves (2x2), mfma_f32_16x16x32_bf16, XOR-swizzled LDS.
__global__ __launch_bounds__(256) void moe_gemm_kernel(
        const float* __restrict__ x, const float* __restrict__ Wp,
        const float* __restrict__ bp, const int* __restrict__ counts,
        const int* __restrict__ start, const int* __restrict__ perm,
        float* __restrict__ out) {
    int e = blockIdx.z;
    int cnt = counts[e];
    int mbase = blockIdx.y * 128;
    if (mbase >= cnt) return;
    int nbase = blockIdx.x * 128;

    __shared__ int rowTok[128];
    __shared__ __align__(16) unsigned short As[128 * BK];
    __shared__ __align__(16) unsigned short Bs[128 * BK];

    int tid = threadIdx.x;
    int lane = tid & 63;
    int wid = tid >> 6;
    int wm = wid >> 1, wn = wid & 1;

    if (tid < 128) {
        int gm = mbase + tid;
        rowTok[tid] = (gm < cnt) ? perm[start[e] + gm] : -1;
    }
    __syncthreads();

    int rowL = tid >> 3;     // 0..31 staging row
    int chunk = tid & 7;     // 0..7  16B chunk within row
    int tokR[4];
#pragma unroll
    for (int p = 0; p < 4; ++p) tokR[p] = rowTok[rowL + p * 32];

    const size_t wpBase = (size_t)e * ODIM * DDIM;

    f32x4 acc[4][4];
#pragma unroll
    for (int m = 0; m < 4; ++m)
#pragma unroll
        for (int n = 0; n < 4; ++n) acc[m][n] = (f32x4){0.f, 0.f, 0.f, 0.f};

    for (int k0 = 0; k0 < DDIM; k0 += BK) {
        // ---- stage A (gathered x rows), fp32 -> bf16, swizzled ----
#pragma unroll
        for (int p = 0; p < 4; ++p) {
            int r = rowL + p * 32;
            int tok = tokR[p];
            float4 v0 = {0.f, 0.f, 0.f, 0.f}, v1 = {0.f, 0.f, 0.f, 0.f};
            if (tok >= 0) {
                const float4* src = (const float4*)(x + (size_t)tok * DDIM + k0 + chunk * 8);
                v0 = src[0]; v1 = src[1];
            }
            uint4 w;
            w.x = (unsigned)f2bf(v0.x) | ((unsigned)f2bf(v0.y) << 16);
            w.y = (unsigned)f2bf(v0.z) | ((unsigned)f2bf(v0.w) << 16);
            w.z = (unsigned)f2bf(v1.x) | ((unsigned)f2bf(v1.y) << 16);
            w.w = (unsigned)f2bf(v1.z) | ((unsigned)f2bf(v1.w) << 16);
            int swz = chunk ^ (r & 7);
            *(uint4*)&As[r * BK + swz * 8] = w;
        }
        // ---- stage B (Wp[e] rows = output cols), fp32 -> bf16, swizzled ----
#pragma unroll
        for (int p = 0; p < 4; ++p) {
            int r = rowL + p * 32;
            const float4* src = (const float4*)(Wp + wpBase + (size_t)(nbase + r) * DDIM + k0 + chunk * 8);
            float4 v0 = src[0], v1 = src[1];
            uint4 w;
            w.x = (unsigned)f2bf(v0.x) | ((unsigned)f2bf(v0.y) << 16);
            w.y = (unsigned)f2bf(v0.z) | ((unsigned)f2bf(v0.w) << 16);
            w.z = (unsigned)f2bf(v1.x) | ((unsigned)f2bf(v1.y) << 16);
            w.w = (unsigned)f2bf(v1.z) | ((unsigned)f2bf(v1.w) << 16);
            int swz = chunk ^ (r & 7);
            *(uint4*)&Bs[r * BK + swz * 8] = w;
        }
        __syncthreads();
#pragma unroll
        for (int kh = 0; kh < 2; ++kh) {
            short8 af[4], bfr[4];
#pragma unroll
            for (int m = 0; m < 4; ++m) {
                int r = wm * 64 + m * 16 + (lane & 15);
                int c = (kh * 4 + (lane >> 4)) ^ (r & 7);
                af[m] = *(const short8*)&As[r * BK + c * 8];
            }
#pragma unroll
            for (int n = 0; n < 4; ++n) {
                int r = wn * 64 + n * 16 + (lane & 15);
                int c = (kh * 4 + (lane >> 4)) ^ (r & 7);
                bfr[n] = *(const short8*)&Bs[r * BK + c * 8];
            }
#pragma unroll
            for (int m = 0; m < 4; ++m)
#pragma unroll
                for (int n = 0; n < 4; ++n)
                    acc[m][n] = __builtin_amdgcn_mfma_f32_16x16x32_bf16(af[m], bfr[n], acc[m][n], 0, 0, 0);
        }
        __syncthreads();
    }

    // ---- epilogue: C/D layout col=lane&15, row=(lane>>4)*4+j ----
    int lcol = lane & 15, lrow4 = (lane >> 4) * 4;
#pragma unroll
    for (int n = 0; n < 4; ++n) {
        int gcol = nbase + wn * 64 + n * 16 + lcol;
        float bias = bp[e * ODIM + gcol];
#pragma unroll
        for (int m = 0; m < 4; ++m) {
#pragma unroll
            for (int j = 0; j < 4; ++j) {
                int rloc = wm * 64 + m * 16 + lrow4 + j;
                int tok = rowTok[rloc];
                if (tok >= 0) out[(size_t)tok * ODIM + gcol] = acc[m][n][j] + bias;
            }
        }
    }
}

extern "C" void kernel_launch(void* const* d_in, const int* in_sizes, int n_in,
                              void* d_out, int out_size, void* d_ws, size_t ws_size,
                              hipStream_t stream) {
    const float* x  = (const float*)d_in[0];
    const float* Wp = (const float*)d_in[1];
    const float* bp = (const float*)d_in[2];
    const float* Wr = (const float*)d_in[3];
    const float* br = (const float*)d_in[4];
    float* out = (float*)d_out;

    char* ws = (char*)d_ws;
    int* layer  = (int*)ws;                    // 8192 ints
    int* counts = (int*)(ws + 32768);          // 8
    int* start  = (int*)(ws + 32768 + 64);     // 8
    int* cursor = (int*)(ws + 32768 + 128);    // 8
    int* perm   = (int*)(ws + 33024);          // 8192 ints

    hipMemsetAsync(counts, 0, 64, stream);

    router_kernel<<<T_TOK / 4, 256, 0, stream>>>(x, Wr, br, layer, counts);
    prefix_loss_kernel<<<1, 64, 0, stream>>>(counts, start, cursor,
                                             out + ((size_t)out_size - 1));
    scatter_kernel<<<T_TOK / 256, 256, 0, stream>>>(layer, cursor, perm);

    dim3 grid(ODIM / 128, T_TOK / 128, NEXP);
    moe_gemm_kernel<<<grid, 256, 0, stream>>>(x, Wp, bp, counts, start, perm, out);
}

// Round 3
// 531.877 us; speedup vs baseline: 1.0544x; 1.0544x over previous
//
#include <hip/hip_runtime.h>
#include <hip/hip_bf16.h>

#define T_TOK 8192
#define DDIM 2048
#define ODIM 2048
#define NEXP 8
#define BK 64

typedef __attribute__((ext_vector_type(8))) short short8;
typedef __attribute__((ext_vector_type(4))) float f32x4;

__device__ inline unsigned short f2bf(float f) {
    union { float f; unsigned u; } c; c.f = f;
    unsigned u = c.u;
    u += 0x7FFF + ((u >> 16) & 1);   // round-to-nearest-even
    return (unsigned short)(u >> 16);
}

__device__ inline void gload_lds16(const void* gsrc, void* lds) {
    __builtin_amdgcn_global_load_lds(
        (const __attribute__((address_space(1))) void*)gsrc,
        (__attribute__((address_space(3))) void*)lds, 16, 0, 0);
}

// ---------------- router: logits = x @ Wr^T + br ; argmax ; counts ; x->bf16 ----------------
__global__ __launch_bounds__(256) void router_kernel(
        const float* __restrict__ x, const float* __restrict__ Wr,
        const float* __restrict__ br, int* __restrict__ layer,
        int* __restrict__ counts, unsigned short* __restrict__ xb) {
    int lane = threadIdx.x & 63;
    int wave = threadIdx.x >> 6;
    int t = blockIdx.x * 4 + wave;
    const float4* xr = (const float4*)(x + (size_t)t * DDIM);
    float acc[NEXP];
#pragma unroll
    for (int e = 0; e < NEXP; ++e) acc[e] = 0.f;
#pragma unroll
    for (int it = 0; it < 8; ++it) {
        int d4 = it * 64 + lane;           // float4 index within row
        float4 xv = xr[d4];
        if (xb) {                          // fused x -> bf16 (wave-uniform branch)
            uint2 w;
            w.x = (unsigned)f2bf(xv.x) | ((unsigned)f2bf(xv.y) << 16);
            w.y = (unsigned)f2bf(xv.z) | ((unsigned)f2bf(xv.w) << 16);
            *(uint2*)&xb[(size_t)t * DDIM + d4 * 4] = w;
        }
#pragma unroll
        for (int e = 0; e < NEXP; ++e) {
            float4 wv = ((const float4*)(Wr + e * DDIM))[d4];
            acc[e] += xv.x * wv.x + xv.y * wv.y + xv.z * wv.z + xv.w * wv.w;
        }
    }
#pragma unroll
    for (int e = 0; e < NEXP; ++e) {
        float v = acc[e];
#pragma unroll
        for (int off = 32; off > 0; off >>= 1) v += __shfl_xor(v, off);
        acc[e] = v;
    }
    if (lane == 0) {
        float best = -1e30f; int arg = 0;
#pragma unroll
        for (int e = 0; e < NEXP; ++e) {
            float v = acc[e] + br[e];
            if (v > best) { best = v; arg = e; }   // strict > keeps first max (np tie-break)
        }
        layer[t] = arg;
        atomicAdd(&counts[arg], 1);
    }
}

// ---------------- Wp fp32 -> bf16 (one pass) ----------------
__global__ __launch_bounds__(256) void cvt_wp_kernel(const float* __restrict__ Wp,
                                                     unsigned short* __restrict__ Wpb) {
    size_t i = ((size_t)blockIdx.x * 256 + threadIdx.x) * 8;
    float4 v0 = ((const float4*)(Wp + i))[0];
    float4 v1 = ((const float4*)(Wp + i))[1];
    uint4 w;
    w.x = (unsigned)f2bf(v0.x) | ((unsigned)f2bf(v0.y) << 16);
    w.y = (unsigned)f2bf(v0.z) | ((unsigned)f2bf(v0.w) << 16);
    w.z = (unsigned)f2bf(v1.x) | ((unsigned)f2bf(v1.y) << 16);
    w.w = (unsigned)f2bf(v1.z) | ((unsigned)f2bf(v1.w) << 16);
    *(uint4*)&Wpb[i] = w;
}

// ---------------- prefix offsets + load-balance loss ----------------
__global__ void prefix_loss_kernel(const int* __restrict__ counts,
                                   int* __restrict__ start, int* __restrict__ cursor,
                                   float* __restrict__ loss_out) {
    if (threadIdx.x == 0) {
        int s = 0;
        for (int e = 0; e < NEXP; ++e) { start[e] = s; cursor[e] = s; s += counts[e]; }
        float mean = (float)T_TOK / (float)NEXP;
        float var = 0.f;
        for (int e = 0; e < NEXP; ++e) { float d = (float)counts[e] - mean; var += d * d; }
        loss_out[0] = (var / (float)NEXP) * 3e-06f;
    }
}

// ---------------- scatter tokens into per-expert buckets ----------------
__global__ __launch_bounds__(256) void scatter_kernel(const int* __restrict__ layer,
                                                      int* __restrict__ cursor,
                                                      int* __restrict__ perm) {
    int t = blockIdx.x * 256 + threadIdx.x;
    int e = layer[t];
    int pos = atomicAdd(&cursor[e], 1);
    perm[pos] = t;
}

// ---------------- grouped GEMM, bf16 path: m97 structure ----------------
// 128x128 tile, BK=64, 4 waves (2x2), global_load_lds w=16, XOR swizzle via
// pre-swizzled global source + swizzled ds_read (both-sides, rule #21).
__global__ __launch_bounds__(256) void moe_gemm_bf16(
        const unsigned short* __restrict__ xb, const unsigned short* __restrict__ Wpb,
        const float* __restrict__ bp, const int* __restrict__ counts,
        const int* __restrict__ start, const int* __restrict__ perm,
        float* __restrict__ out) {
    int e = blockIdx.z;
    int cnt = counts[e];
    int mbase = blockIdx.y * 128;
    if (mbase >= cnt) return;
    int nbase = blockIdx.x * 128;

    __shared__ int rowTok[128];
    __shared__ __align__(16) unsigned short As[128 * BK];   // 16 KB
    __shared__ __align__(16) unsigned short Bs[128 * BK];   // 16 KB

    int tid = threadIdx.x;
    int lane = tid & 63;
    int wid = tid >> 6;
    int wm = wid >> 1, wn = wid & 1;

    if (tid < 128) {
        int gm = mbase + tid;
        rowTok[tid] = (gm < cnt) ? perm[start[e] + gm] : -1;
    }
    __syncthreads();

    // staging geometry: instr q = wid*4+i covers rows q*8..q*8+7 (1 KB each).
    // lane: subrow = lane>>3, phys chunk p = lane&7 (linear LDS dest),
    // logical chunk c = p ^ (row&7) = (lane&7) ^ subrow  (row&7 == subrow).
    int subrow = lane >> 3;
    int c = (lane & 7) ^ subrow;
    const size_t eoff = (size_t)e * ODIM * DDIM;

    const unsigned short* aSrc[4];
    const unsigned short* bSrc[4];
    unsigned short* aDst[4];
    unsigned short* bDst[4];
#pragma unroll
    for (int i = 0; i < 4; ++i) {
        int row = wid * 32 + i * 8 + subrow;
        int tok = rowTok[row]; if (tok < 0) tok = 0;        // masked in epilogue
        aSrc[i] = xb + (size_t)tok * DDIM + c * 8;
        bSrc[i] = Wpb + eoff + (size_t)(nbase + row) * DDIM + c * 8;
        aDst[i] = &As[(wid * 4 + i) * 512];                 // 1 KB per instr
        bDst[i] = &Bs[(wid * 4 + i) * 512];
    }

    f32x4 acc[4][4];
#pragma unroll
    for (int m = 0; m < 4; ++m)
#pragma unroll
        for (int n = 0; n < 4; ++n) acc[m][n] = (f32x4){0.f, 0.f, 0.f, 0.f};

    for (int k0 = 0; k0 < DDIM; k0 += BK) {
#pragma unroll
        for (int i = 0; i < 4; ++i) gload_lds16(aSrc[i] + k0, aDst[i]);
#pragma unroll
        for (int i = 0; i < 4; ++i) gload_lds16(bSrc[i] + k0, bDst[i]);
        __syncthreads();   // compiler drains vmcnt before barrier
#pragma unroll
        for (int kh = 0; kh < 2; ++kh) {
            short8 af[4], bfr[4];
#pragma unroll
            for (int m = 0; m < 4; ++m) {
                int r = wm * 64 + m * 16 + (lane & 15);
                int p = (kh * 4 + (lane >> 4)) ^ (r & 7);
                af[m] = *(const short8*)&As[r * BK + p * 8];
            }
#pragma unroll
            for (int n = 0; n < 4; ++n) {
                int r = wn * 64 + n * 16 + (lane & 15);
                int p = (kh * 4 + (lane >> 4)) ^ (r & 7);
                bfr[n] = *(const short8*)&Bs[r * BK + p * 8];
            }
#pragma unroll
            for (int m = 0; m < 4; ++m)
#pragma unroll
                for (int n = 0; n < 4; ++n)
                    acc[m][n] = __builtin_amdgcn_mfma_f32_16x16x32_bf16(af[m], bfr[n], acc[m][n], 0, 0, 0);
        }
        __syncthreads();
    }

    // epilogue: C/D layout col=lane&15, row=(lane>>4)*4+j
    int lcol = lane & 15, lrow4 = (lane >> 4) * 4;
#pragma unroll
    for (int n = 0; n < 4; ++n) {
        int gcol = nbase + wn * 64 + n * 16 + lcol;
        float bias = bp[e * ODIM + gcol];
#pragma unroll
        for (int m = 0; m < 4; ++m) {
#pragma unroll
            for (int j = 0; j < 4; ++j) {
                int rloc = wm * 64 + m * 16 + lrow4 + j;
                int tok = rowTok[rloc];
                if (tok >= 0) out[(size_t)tok * ODIM + gcol] = acc[m][n][j] + bias;
            }
        }
    }
}

// ---------------- fallback GEMM (fp32 on-the-fly conversion), from R0 ----------------
__global__ __launch_bounds__(256) void moe_gemm_kernel(
        const float* __restrict__ x, const float* __restrict__ Wp,
        const float* __restrict__ bp, const int* __restrict__ counts,
        const int* __restrict__ start, const int* __restrict__ perm,
        float* __restrict__ out) {
    int e = blockIdx.z;
    int cnt = counts[e];
    int mbase = blockIdx.y * 128;
    if (mbase >= cnt) return;
    int nbase = blockIdx.x * 128;

    __shared__ int rowTok[128];
    __shared__ __align__(16) unsigned short As[128 * BK];
    __shared__ __align__(16) unsigned short Bs[128 * BK];

    int tid = threadIdx.x;
    int lane = tid & 63;
    int wid = tid >> 6;
    int wm = wid >> 1, wn = wid & 1;

    if (tid < 128) {
        int gm = mbase + tid;
        rowTok[tid] = (gm < cnt) ? perm[start[e] + gm] : -1;
    }
    __syncthreads();

    int rowL = tid >> 3;
    int chunk = tid & 7;
    int tokR[4];
#pragma unroll
    for (int p = 0; p < 4; ++p) tokR[p] = rowTok[rowL + p * 32];

    const size_t wpBase = (size_t)e * ODIM * DDIM;

    f32x4 acc[4][4];
#pragma unroll
    for (int m = 0; m < 4; ++m)
#pragma unroll
        for (int n = 0; n < 4; ++n) acc[m][n] = (f32x4){0.f, 0.f, 0.f, 0.f};

    for (int k0 = 0; k0 < DDIM; k0 += BK) {
#pragma unroll
        for (int p = 0; p < 4; ++p) {
            int r = rowL + p * 32;
            int tok = tokR[p];
            float4 v0 = {0.f, 0.f, 0.f, 0.f}, v1 = {0.f, 0.f, 0.f, 0.f};
            if (tok >= 0) {
                const float4* src = (const float4*)(x + (size_t)tok * DDIM + k0 + chunk * 8);
                v0 = src[0]; v1 = src[1];
            }
            uint4 w;
            w.x = (unsigned)f2bf(v0.x) | ((unsigned)f2bf(v0.y) << 16);
            w.y = (unsigned)f2bf(v0.z) | ((unsigned)f2bf(v0.w) << 16);
            w.z = (unsigned)f2bf(v1.x) | ((unsigned)f2bf(v1.y) << 16);
            w.w = (unsigned)f2bf(v1.z) | ((unsigned)f2bf(v1.w) << 16);
            int swz = chunk ^ (r & 7);
            *(uint4*)&As[r * BK + swz * 8] = w;
        }
#pragma unroll
        for (int p = 0; p < 4; ++p) {
            int r = rowL + p * 32;
            const float4* src = (const float4*)(Wp + wpBase + (size_t)(nbase + r) * DDIM + k0 + chunk * 8);
            float4 v0 = src[0], v1 = src[1];
            uint4 w;
            w.x = (unsigned)f2bf(v0.x) | ((unsigned)f2bf(v0.y) << 16);
            w.y = (unsigned)f2bf(v0.z) | ((unsigned)f2bf(v0.w) << 16);
            w.z = (unsigned)f2bf(v1.x) | ((unsigned)f2bf(v1.y) << 16);
            w.w = (unsigned)f2bf(v1.z) | ((unsigned)f2bf(v1.w) << 16);
            int swz = chunk ^ (r & 7);
            *(uint4*)&Bs[r * BK + swz * 8] = w;
        }
        __syncthreads();
#pragma unroll
        for (int kh = 0; kh < 2; ++kh) {
            short8 af[4], bfr[4];
#pragma unroll
            for (int m = 0; m < 4; ++m) {
                int r = wm * 64 + m * 16 + (lane & 15);
                int c2 = (kh * 4 + (lane >> 4)) ^ (r & 7);
                af[m] = *(const short8*)&As[r * BK + c2 * 8];
            }
#pragma unroll
            for (int n = 0; n < 4; ++n) {
                int r = wn * 64 + n * 16 + (lane & 15);
                int c2 = (kh * 4 + (lane >> 4)) ^ (r & 7);
                bfr[n] = *(const short8*)&Bs[r * BK + c2 * 8];
            }
#pragma unroll
            for (int m = 0; m < 4; ++m)
#pragma unroll
                for (int n = 0; n < 4; ++n)
                    acc[m][n] = __builtin_amdgcn_mfma_f32_16x16x32_bf16(af[m], bfr[n], acc[m][n], 0, 0, 0);
        }
        __syncthreads();
    }

    int lcol = lane & 15, lrow4 = (lane >> 4) * 4;
#pragma unroll
    for (int n = 0; n < 4; ++n) {
        int gcol = nbase + wn * 64 + n * 16 + lcol;
        float bias = bp[e * ODIM + gcol];
#pragma unroll
        for (int m = 0; m < 4; ++m) {
#pragma unroll
            for (int j = 0; j < 4; ++j) {
                int rloc = wm * 64 + m * 16 + lrow4 + j;
                int tok = rowTok[rloc];
                if (tok >= 0) out[(size_t)tok * ODIM + gcol] = acc[m][n][j] + bias;
            }
        }
    }
}

extern "C" void kernel_launch(void* const* d_in, const int* in_sizes, int n_in,
                              void* d_out, int out_size, void* d_ws, size_t ws_size,
                              hipStream_t stream) {
    const float* x  = (const float*)d_in[0];
    const float* Wp = (const float*)d_in[1];
    const float* bp = (const float*)d_in[2];
    const float* Wr = (const float*)d_in[3];
    const float* br = (const float*)d_in[4];
    float* out = (float*)d_out;

    char* ws = (char*)d_ws;
    int* layer  = (int*)ws;                    // 8192 ints  (32768 B)
    int* counts = (int*)(ws + 32768);          // 8
    int* start  = (int*)(ws + 32832);          // 8
    int* cursor = (int*)(ws + 32896);          // 8
    int* perm   = (int*)(ws + 33024);          // 8192 ints  (32768 B) -> ends 65792

    const size_t XB_OFF  = 65792;                                  // 32 MB x-bf16
    const size_t WPB_OFF = XB_OFF + (size_t)T_TOK * DDIM * 2;      // 64 MB Wp-bf16
    const size_t NEED    = WPB_OFF + (size_t)NEXP * ODIM * DDIM * 2;
    bool fast = ws_size >= NEED;

    unsigned short* xb  = fast ? (unsigned short*)(ws + XB_OFF)  : nullptr;
    unsigned short* wpb = fast ? (unsigned short*)(ws + WPB_OFF) : nullptr;

    hipMemsetAsync(counts, 0, 64, stream);

    router_kernel<<<T_TOK / 4, 256, 0, stream>>>(x, Wr, br, layer, counts, xb);
    prefix_loss_kernel<<<1, 64, 0, stream>>>(counts, start, cursor,
                                             out + ((size_t)out_size - 1));
    scatter_kernel<<<T_TOK / 256, 256, 0, stream>>>(layer, cursor, perm);

    dim3 grid(ODIM / 128, T_TOK / 128, NEXP);
    if (fast) {
        cvt_wp_kernel<<<(NEXP * ODIM * DDIM) / (256 * 8), 256, 0, stream>>>(Wp, wpb);
        moe_gemm_bf16<<<grid, 256, 0, stream>>>(xb, wpb, bp, counts, start, perm, out);
    } else {
        moe_gemm_kernel<<<grid, 256, 0, stream>>>(x, Wp, bp, counts, start, perm, out);
    }
}